// Round 3
// baseline (1221.197 us; speedup 1.0000x reference)
//
#include <hip/hip_runtime.h>
#include <stdint.h>

#define DIM 128

static inline int cdiv(long a, long b) { return (int)((a + b - 1) / b); }

// ---- index conversion: handles both int32 and int64 edge_index layouts ----
__global__ __launch_bounds__(256) void convert_idx_kernel(
    const int* __restrict__ raw, int* __restrict__ out, long n_total) {
  bool is64;
  {
    int l = threadIdx.x & 63;
    int v = raw[2 * l + 1];               // high words if int64 (values < 2^31)
    unsigned long long m = __ballot(v == 0);
    is64 = (m == ~0ull);
  }
  long i = blockIdx.x * 256L + threadIdx.x;
  if (i < n_total) out[i] = is64 ? raw[2 * i] : raw[i];
}

// cnt[0..E) = hyperedge sizes, cnt[E..E+N) = node degrees
__global__ __launch_bounds__(256) void count_kernel(
    const int* __restrict__ src, const int* __restrict__ edg,
    int* __restrict__ cnt, int E, int nnz) {
  int g = blockIdx.x * 256 + threadIdx.x;
  if (g < nnz) {
    atomicAdd(&cnt[edg[g]], 1);
    atomicAdd(&cnt[E + src[g]], 1);
  }
}

// ---- 3-kernel exclusive scan of cnt[0..M) into P[0..M], P[M]=total ----
__global__ __launch_bounds__(256) void scanA_kernel(
    const int* __restrict__ cnt, int* __restrict__ P, int* __restrict__ BS, int M) {
  __shared__ int lds[256];
  int t = threadIdx.x;
  long base = blockIdx.x * 1024L;
  int v[4], ts = 0;
#pragma unroll
  for (int j = 0; j < 4; ++j) {
    long i = base + t * 4 + j;
    v[j] = (i < M) ? cnt[i] : 0;
    ts += v[j];
  }
  lds[t] = ts;
  __syncthreads();
  for (int off = 1; off < 256; off <<= 1) {
    int x = (t >= off) ? lds[t - off] : 0;
    __syncthreads();
    lds[t] += x;
    __syncthreads();
  }
  int run = lds[t] - ts;  // exclusive base for this thread
#pragma unroll
  for (int j = 0; j < 4; ++j) {
    long i = base + t * 4 + j;
    if (i < M) P[i] = run;
    run += v[j];
  }
  if (t == 255) BS[blockIdx.x] = lds[255];
}

__global__ void scanB_kernel(int* __restrict__ BS, int* __restrict__ P,
                             int nblocks, int M) {
  if (threadIdx.x == 0) {
    int run = 0;
    for (int i = 0; i < nblocks; ++i) { int x = BS[i]; BS[i] = run; run += x; }
    P[M] = run;
  }
}

__global__ __launch_bounds__(256) void scanC_kernel(
    int* __restrict__ P, const int* __restrict__ BS, int M) {
  long i = blockIdx.x * 256L + threadIdx.x;
  if (i < M) P[i] += BS[i >> 10];
}

// adj_e[P[e]..] = member nodes of edge e ; adj_n[P[E+i]-nnz..] = edges of node i
__global__ __launch_bounds__(256) void fill_adj_kernel(
    const int* __restrict__ src, const int* __restrict__ edg,
    const int* __restrict__ P, int* __restrict__ cnt,
    int* __restrict__ adj_e, int* __restrict__ adj_n, int E, int nnz) {
  int g = blockIdx.x * 256 + threadIdx.x;
  if (g < nnz) {
    int e = edg[g], s = src[g];
    int pe = P[e] + atomicAdd(&cnt[e], 1);
    adj_e[pe] = s;
    int pn = P[E + s] - nnz + atomicAdd(&cnt[E + s], 1);
    adj_n[pn] = e;
  }
}

// Wp = diag(a) @ W ; rvec = d @ W   (folds previous layer's BN affine into GEMM)
__global__ void prep_w_kernel(const float* __restrict__ W,
                              const float* __restrict__ aff_a,
                              const float* __restrict__ aff_d,
                              float* __restrict__ Wp, float* __restrict__ rvec,
                              int has_aff) {
  int j = threadIdx.x;  // 0..127
  float racc = 0.0f;
  for (int c = 0; c < DIM; ++c) {
    float w = W[c * DIM + j];
    float a = has_aff ? aff_a[c] : 1.0f;
    float d = has_aff ? aff_d[c] : 0.0f;
    Wp[c * DIM + j] = a * w;
    racc = fmaf(d, w, racc);
  }
  rvec[j] = racc;
}

// Y[N x 128] = X @ Wp + rvec (all fp32).
// In-place safe (X == Y): each block reads only its own 128 rows, and all its
// global reads complete (block barrier) before any of its stores.
__global__ __launch_bounds__(256) void gemm128_kernel(
    const float* __restrict__ X, const float* __restrict__ Wp,
    const float* __restrict__ rvec, float* __restrict__ Y, int nrows) {
  __shared__ float sW[32 * DIM];   // sW[kk*128 + j]
  __shared__ float sX[DIM * 36];   // sX[rr*36 + kk], 36 keeps 16B align + pad
  const int t = threadIdx.x;
  const int row0 = blockIdx.x * DIM;
  const int tx = t & 15, ty = t >> 4;
  const int col0 = tx * 8, lr0 = ty * 8;
  float acc[8][8];
#pragma unroll
  for (int i = 0; i < 8; ++i)
#pragma unroll
    for (int j = 0; j < 8; ++j) acc[i][j] = 0.0f;

  for (int kc = 0; kc < 4; ++kc) {
    __syncthreads();
    {
      const float4* W4 = (const float4*)(Wp + kc * 32 * DIM);
      float4* sW4 = (float4*)sW;
#pragma unroll
      for (int i = 0; i < 4; ++i) sW4[t + i * 256] = W4[t + i * 256];
    }
#pragma unroll
    for (int i = 0; i < 4; ++i) {
      int q = t + i * 256;            // 0..1023 float4 slots
      int rr = q >> 3, kq = q & 7;
      int gr = row0 + rr; if (gr >= nrows) gr = nrows - 1;  // stores are guarded
      float4 v = *(const float4*)&X[(size_t)gr * DIM + kc * 32 + kq * 4];
      *(float4*)&sX[rr * 36 + kq * 4] = v;
    }
    __syncthreads();
    for (int kk = 0; kk < 32; ++kk) {
      float4 w0 = *(const float4*)&sW[kk * DIM + col0];
      float4 w1 = *(const float4*)&sW[kk * DIM + col0 + 4];
      float wv[8] = {w0.x, w0.y, w0.z, w0.w, w1.x, w1.y, w1.z, w1.w};
      float xv[8];
#pragma unroll
      for (int i = 0; i < 8; ++i) xv[i] = sX[(lr0 + i) * 36 + kk];
#pragma unroll
      for (int i = 0; i < 8; ++i)
#pragma unroll
        for (int j = 0; j < 8; ++j) acc[i][j] = fmaf(xv[i], wv[j], acc[i][j]);
    }
  }
  float4 r0 = *(const float4*)&rvec[col0];
  float4 r1 = *(const float4*)&rvec[col0 + 4];
#pragma unroll
  for (int i = 0; i < 8; ++i) {
    int gr = row0 + lr0 + i;
    if (gr < nrows) {
      float4 o0, o1;
      o0.x = acc[i][0] + r0.x; o0.y = acc[i][1] + r0.y;
      o0.z = acc[i][2] + r0.z; o0.w = acc[i][3] + r0.w;
      o1.x = acc[i][4] + r1.x; o1.y = acc[i][5] + r1.y;
      o1.z = acc[i][6] + r1.z; o1.w = acc[i][7] + r1.w;
      *(float4*)&Y[(size_t)gr * DIM + col0]     = o0;
      *(float4*)&Y[(size_t)gr * DIM + col0 + 4] = o1;
    }
  }
}

// ef[e][c] = Binv_e * sum_{s in e} Y[s][c]   (gather; one block per edge)
__global__ __launch_bounds__(128) void edge_gather_kernel(
    const float* __restrict__ Y, const int* __restrict__ P,
    const int* __restrict__ adj_e, float* __restrict__ ef, int E) {
  int e = blockIdx.x;
  int c = threadIdx.x;
  int p0 = P[e], p1 = P[e + 1];
  float s = 0.0f;
  for (int k = p0; k < p1; ++k) {
    int n = adj_e[k];
    s += Y[(size_t)n * DIM + c];
  }
  float binv = (p1 > p0) ? 1.0f / (float)(p1 - p0) : 0.0f;
  ef[(size_t)e * DIM + c] = s * binv;
}

// z[i][c] = relu(Dinv_i * sum_{e ni i} ef[e][c] + b_c), fused BN stats
__global__ __launch_bounds__(128) void node_gather_kernel(
    const float* __restrict__ ef, const int* __restrict__ P,
    const int* __restrict__ adj_n, const float* __restrict__ b,
    float* __restrict__ z, float* __restrict__ sum,
    float* __restrict__ sumsq, int E, int N, int nnz) {
  int c = threadIdx.x;
  float bc = b[c];
  float s1 = 0.0f, s2 = 0.0f;
  for (int i = blockIdx.x; i < N; i += gridDim.x) {
    int p0 = P[E + i] - nnz, p1 = P[E + i + 1] - nnz;
    float a = 0.0f;
    for (int k = p0; k < p1; ++k) {
      int e = adj_n[k];
      a += ef[(size_t)e * DIM + c];
    }
    float dinv = (p1 > p0) ? 1.0f / (float)(p1 - p0) : 0.0f;
    float v = fmaxf(fmaf(dinv, a, bc), 0.0f);
    z[(size_t)i * DIM + c] = v;
    s1 += v;
    s2 = fmaf(v, v, s2);
  }
  atomicAdd(&sum[c], s1);
  atomicAdd(&sumsq[c], s2);
}

// aff_a = g*rsqrt(var+eps); aff_d = beta - mu*aff_a
__global__ void finalize_bn_kernel(const float* __restrict__ sum,
                                   const float* __restrict__ sumsq,
                                   const float* __restrict__ g,
                                   const float* __restrict__ beta,
                                   float* __restrict__ aff_a, float* __restrict__ aff_d,
                                   int n) {
  int c = threadIdx.x;
  float inv_n = 1.0f / (float)n;
  float mu = sum[c] * inv_n;
  float var = fmaf(sumsq[c], inv_n, -mu * mu);
  float a = g[c] * rsqrtf(var + 1e-5f);
  aff_a[c] = a;
  aff_d[c] = fmaf(-mu, a, beta[c]);
}

// out = aff_a*z + aff_d (fp32, in-place safe: pure elementwise)
__global__ __launch_bounds__(256) void apply_affine_kernel(
    const float* __restrict__ zin, const float* __restrict__ aff_a,
    const float* __restrict__ aff_d, float* __restrict__ out, long total4) {
  long i = blockIdx.x * 256L + threadIdx.x;
  if (i >= total4) return;
  int c4 = (int)(i & 31);
  float4 a = ((const float4*)aff_a)[c4];
  float4 d = ((const float4*)aff_d)[c4];
  float4 v = ((const float4*)zin)[i];
  float4 o;
  o.x = fmaf(a.x, v.x, d.x);
  o.y = fmaf(a.y, v.y, d.y);
  o.z = fmaf(a.z, v.z, d.z);
  o.w = fmaf(a.w, v.w, d.w);
  ((float4*)out)[i] = o;
}

extern "C" void kernel_launch(void* const* d_in, const int* in_sizes, int n_in,
                              void* d_out, int out_size, void* d_ws, size_t ws_size,
                              hipStream_t stream) {
  const int NNZv = in_sizes[0] / 2;
  const int Nv   = in_sizes[1] / DIM;
  const int Ev   = in_sizes[2] / DIM;
  const int* eidx_raw = (const int*)d_in[0];
  const float* node_attr = (const float*)d_in[1];

  // ---- workspace layout (~21 MB total) ----
  float* bufE  = (float*)d_ws;                 // E*128 f32
  float* Wp    = bufE + (size_t)Ev * DIM;      // 128*128
  float* rvec  = Wp + DIM * DIM;               // 128
  float* sums  = rvec + 128;                   // 128
  float* sumsq = sums + 128;                   // 128
  float* aff_a = sumsq + 128;                  // 128
  float* aff_d = aff_a + 128;                  // 128
  int* src   = (int*)(aff_d + 128);            // NNZ
  int* edg   = src + NNZv;                     // NNZ
  int* P     = edg + NNZv;                     // E+N+1
  int* BS    = P + (Ev + Nv + 1);              // <=256 block sums
  int* cnt   = BS + 256;                       // E+N
  int* adj_e = cnt + (Ev + Nv);                // NNZ
  int* adj_n = adj_e + NNZv;                   // NNZ
  float* Ybuf = (float*)d_out;                 // Y and z time-share d_out

  const int M = Ev + Nv;
  const int nbA = cdiv(M, 1024);

  convert_idx_kernel<<<cdiv(2L * NNZv, 256), 256, 0, stream>>>(eidx_raw, src, 2L * NNZv);
  hipMemsetAsync(cnt, 0, (size_t)M * 4, stream);
  count_kernel<<<cdiv(NNZv, 256), 256, 0, stream>>>(src, edg, cnt, Ev, NNZv);
  scanA_kernel<<<nbA, 256, 0, stream>>>(cnt, P, BS, M);
  scanB_kernel<<<1, 64, 0, stream>>>(BS, P, nbA, M);
  scanC_kernel<<<cdiv(M, 256), 256, 0, stream>>>(P, BS, M);
  hipMemsetAsync(cnt, 0, (size_t)M * 4, stream);
  fill_adj_kernel<<<cdiv(NNZv, 256), 256, 0, stream>>>(src, edg, P, cnt, adj_e, adj_n, Ev, NNZv);

  const float* Xin = node_attr;
  for (int l = 0; l < 3; ++l) {
    const float* W    = (const float*)d_in[3 + l * 4];
    const float* b    = (const float*)d_in[4 + l * 4];
    const float* g    = (const float*)d_in[5 + l * 4];
    const float* beta = (const float*)d_in[6 + l * 4];

    prep_w_kernel<<<1, 128, 0, stream>>>(W, aff_a, aff_d, Wp, rvec, l > 0 ? 1 : 0);
    gemm128_kernel<<<cdiv(Nv, DIM), 256, 0, stream>>>(Xin, Wp, rvec, Ybuf, Nv);
    edge_gather_kernel<<<Ev, 128, 0, stream>>>(Ybuf, P, adj_e, bufE, Ev);
    hipMemsetAsync(sums, 0, 256 * 4, stream);
    node_gather_kernel<<<2048, 128, 0, stream>>>(bufE, P, adj_n, b, Ybuf, sums, sumsq,
                                                 Ev, Nv, NNZv);
    finalize_bn_kernel<<<1, 128, 0, stream>>>(sums, sumsq, g, beta, aff_a, aff_d, Nv);
    Xin = Ybuf;
  }
  apply_affine_kernel<<<cdiv((long)Nv * DIM / 4, 256), 256, 0, stream>>>(
      Ybuf, aff_a, aff_d, (float*)d_out, (long)Nv * DIM / 4);
}

// Round 4
// 992.671 us; speedup vs baseline: 1.2302x; 1.2302x over previous
//
#include <hip/hip_runtime.h>
#include <stdint.h>

#define DIM 128

static inline int cdiv(long a, long b) { return (int)((a + b - 1) / b); }

// ---- index conversion: handles both int32 and int64 edge_index layouts ----
__global__ __launch_bounds__(256) void convert_idx_kernel(
    const int* __restrict__ raw, int* __restrict__ out, long n_total) {
  bool is64;
  {
    int l = threadIdx.x & 63;
    int v = raw[2 * l + 1];               // high words if int64 (values < 2^31)
    unsigned long long m = __ballot(v == 0);
    is64 = (m == ~0ull);
  }
  long i = blockIdx.x * 256L + threadIdx.x;
  if (i < n_total) out[i] = is64 ? raw[2 * i] : raw[i];
}

// cnt[0..E) = hyperedge sizes, cnt[E..E+N) = node degrees
__global__ __launch_bounds__(256) void count_kernel(
    const int* __restrict__ src, const int* __restrict__ edg,
    int* __restrict__ cnt, int E, int nnz) {
  int g = blockIdx.x * 256 + threadIdx.x;
  if (g < nnz) {
    atomicAdd(&cnt[edg[g]], 1);
    atomicAdd(&cnt[E + src[g]], 1);
  }
}

// ---- 3-kernel exclusive scan of cnt[0..M) into P[0..M], P[M]=total ----
__global__ __launch_bounds__(256) void scanA_kernel(
    const int* __restrict__ cnt, int* __restrict__ P, int* __restrict__ BS, int M) {
  __shared__ int lds[256];
  int t = threadIdx.x;
  long base = blockIdx.x * 1024L;
  int v[4], ts = 0;
#pragma unroll
  for (int j = 0; j < 4; ++j) {
    long i = base + t * 4 + j;
    v[j] = (i < M) ? cnt[i] : 0;
    ts += v[j];
  }
  lds[t] = ts;
  __syncthreads();
  for (int off = 1; off < 256; off <<= 1) {
    int x = (t >= off) ? lds[t - off] : 0;
    __syncthreads();
    lds[t] += x;
    __syncthreads();
  }
  int run = lds[t] - ts;  // exclusive base for this thread
#pragma unroll
  for (int j = 0; j < 4; ++j) {
    long i = base + t * 4 + j;
    if (i < M) P[i] = run;
    run += v[j];
  }
  if (t == 255) BS[blockIdx.x] = lds[255];
}

__global__ void scanB_kernel(int* __restrict__ BS, int* __restrict__ P,
                             int nblocks, int M) {
  if (threadIdx.x == 0) {
    int run = 0;
    for (int i = 0; i < nblocks; ++i) { int x = BS[i]; BS[i] = run; run += x; }
    P[M] = run;
  }
}

__global__ __launch_bounds__(256) void scanC_kernel(
    int* __restrict__ P, const int* __restrict__ BS, int M) {
  long i = blockIdx.x * 256L + threadIdx.x;
  if (i < M) P[i] += BS[i >> 10];
}

// adj_e[P[e]..] = member nodes of edge e ; adj_n[P[E+i]-nnz..] = edges of node i
__global__ __launch_bounds__(256) void fill_adj_kernel(
    const int* __restrict__ src, const int* __restrict__ edg,
    const int* __restrict__ P, int* __restrict__ cnt,
    int* __restrict__ adj_e, int* __restrict__ adj_n, int E, int nnz) {
  int g = blockIdx.x * 256 + threadIdx.x;
  if (g < nnz) {
    int e = edg[g], s = src[g];
    int pe = P[e] + atomicAdd(&cnt[e], 1);
    adj_e[pe] = s;
    int pn = P[E + s] - nnz + atomicAdd(&cnt[E + s], 1);
    adj_n[pn] = e;
  }
}

// Wp = diag(a) @ W ; rvec = d @ W   (folds previous layer's BN affine into GEMM)
__global__ void prep_w_kernel(const float* __restrict__ W,
                              const float* __restrict__ aff_a,
                              const float* __restrict__ aff_d,
                              float* __restrict__ Wp, float* __restrict__ rvec,
                              int has_aff) {
  int j = threadIdx.x;  // 0..127
  float racc = 0.0f;
  for (int c = 0; c < DIM; ++c) {
    float w = W[c * DIM + j];
    float a = has_aff ? aff_a[c] : 1.0f;
    float d = has_aff ? aff_d[c] : 0.0f;
    Wp[c * DIM + j] = a * w;
    racc = fmaf(d, w, racc);
  }
  rvec[j] = racc;
}

// Y[N x 128] = X @ Wp + rvec (all fp32).
// In-place safe (X == Y): each block reads only its own 128 rows, and all its
// global reads complete (block barrier) before any of its stores.
__global__ __launch_bounds__(256) void gemm128_kernel(
    const float* __restrict__ X, const float* __restrict__ Wp,
    const float* __restrict__ rvec, float* __restrict__ Y, int nrows) {
  __shared__ float sW[32 * DIM];   // sW[kk*128 + j]
  __shared__ float sX[DIM * 36];   // sX[rr*36 + kk], 36 keeps 16B align + pad
  const int t = threadIdx.x;
  const int row0 = blockIdx.x * DIM;
  const int tx = t & 15, ty = t >> 4;
  const int col0 = tx * 8, lr0 = ty * 8;
  float acc[8][8];
#pragma unroll
  for (int i = 0; i < 8; ++i)
#pragma unroll
    for (int j = 0; j < 8; ++j) acc[i][j] = 0.0f;

  for (int kc = 0; kc < 4; ++kc) {
    __syncthreads();
    {
      const float4* W4 = (const float4*)(Wp + kc * 32 * DIM);
      float4* sW4 = (float4*)sW;
#pragma unroll
      for (int i = 0; i < 4; ++i) sW4[t + i * 256] = W4[t + i * 256];
    }
#pragma unroll
    for (int i = 0; i < 4; ++i) {
      int q = t + i * 256;            // 0..1023 float4 slots
      int rr = q >> 3, kq = q & 7;
      int gr = row0 + rr; if (gr >= nrows) gr = nrows - 1;  // stores are guarded
      float4 v = *(const float4*)&X[(size_t)gr * DIM + kc * 32 + kq * 4];
      *(float4*)&sX[rr * 36 + kq * 4] = v;
    }
    __syncthreads();
    for (int kk = 0; kk < 32; ++kk) {
      float4 w0 = *(const float4*)&sW[kk * DIM + col0];
      float4 w1 = *(const float4*)&sW[kk * DIM + col0 + 4];
      float wv[8] = {w0.x, w0.y, w0.z, w0.w, w1.x, w1.y, w1.z, w1.w};
      float xv[8];
#pragma unroll
      for (int i = 0; i < 8; ++i) xv[i] = sX[(lr0 + i) * 36 + kk];
#pragma unroll
      for (int i = 0; i < 8; ++i)
#pragma unroll
        for (int j = 0; j < 8; ++j) acc[i][j] = fmaf(xv[i], wv[j], acc[i][j]);
    }
  }
  float4 r0 = *(const float4*)&rvec[col0];
  float4 r1 = *(const float4*)&rvec[col0 + 4];
#pragma unroll
  for (int i = 0; i < 8; ++i) {
    int gr = row0 + lr0 + i;
    if (gr < nrows) {
      float4 o0, o1;
      o0.x = acc[i][0] + r0.x; o0.y = acc[i][1] + r0.y;
      o0.z = acc[i][2] + r0.z; o0.w = acc[i][3] + r0.w;
      o1.x = acc[i][4] + r1.x; o1.y = acc[i][5] + r1.y;
      o1.z = acc[i][6] + r1.z; o1.w = acc[i][7] + r1.w;
      *(float4*)&Y[(size_t)gr * DIM + col0]     = o0;
      *(float4*)&Y[(size_t)gr * DIM + col0 + 4] = o1;
    }
  }
}

// ef[e][c] = Binv_e * sum_{s in e} Y[s][c]
// 32 lanes/edge (float4 each), 8 edge-slots per 256-thread block, 2x unroll.
__global__ __launch_bounds__(256) void edge_gather_kernel(
    const float* __restrict__ Y, const int* __restrict__ P,
    const int* __restrict__ adj_e, float* __restrict__ ef, int E) {
  int slot = threadIdx.x >> 5;
  int l = threadIdx.x & 31;
  int e = blockIdx.x * 8 + slot;
  if (e >= E) return;
  int p0 = P[e], p1 = P[e + 1];
  const float4* Y4 = (const float4*)Y;
  float4 acc = {0.f, 0.f, 0.f, 0.f};
  int k = p0;
  for (; k + 1 < p1; k += 2) {
    int n0 = adj_e[k], n1 = adj_e[k + 1];
    float4 a0 = Y4[(size_t)n0 * 32 + l];
    float4 a1 = Y4[(size_t)n1 * 32 + l];
    acc.x += a0.x + a1.x; acc.y += a0.y + a1.y;
    acc.z += a0.z + a1.z; acc.w += a0.w + a1.w;
  }
  if (k < p1) {
    float4 a0 = Y4[(size_t)adj_e[k] * 32 + l];
    acc.x += a0.x; acc.y += a0.y; acc.z += a0.z; acc.w += a0.w;
  }
  float binv = (p1 > p0) ? 1.0f / (float)(p1 - p0) : 0.0f;
  acc.x *= binv; acc.y *= binv; acc.z *= binv; acc.w *= binv;
  ((float4*)ef)[(size_t)e * 32 + l] = acc;
}

// z[i][c] = relu(Dinv_i * sum_{e ni i} ef[e][c] + b_c), fused BN stats.
// 32 lanes/node (float4), 8 node-slots per block, grid-stride, LDS-reduced stats.
__global__ __launch_bounds__(256) void node_gather_kernel(
    const float* __restrict__ ef, const int* __restrict__ P,
    const int* __restrict__ adj_n, const float* __restrict__ b,
    float* __restrict__ z, float* __restrict__ sum,
    float* __restrict__ sumsq, int E, int N, int nnz) {
  __shared__ float lsum[DIM], lsumsq[DIM];
  int t = threadIdx.x;
  if (t < DIM) { lsum[t] = 0.f; lsumsq[t] = 0.f; }
  __syncthreads();
  int slot = t >> 5;
  int l = t & 31;
  const float4* ef4 = (const float4*)ef;
  float4 bc = ((const float4*)b)[l];
  float4 s1 = {0.f, 0.f, 0.f, 0.f}, s2 = {0.f, 0.f, 0.f, 0.f};
  for (int i = blockIdx.x * 8 + slot; i < N; i += gridDim.x * 8) {
    int p0 = P[E + i] - nnz, p1 = P[E + i + 1] - nnz;
    float4 a = {0.f, 0.f, 0.f, 0.f};
    int k = p0;
    for (; k + 1 < p1; k += 2) {
      int e0 = adj_n[k], e1 = adj_n[k + 1];
      float4 a0 = ef4[(size_t)e0 * 32 + l];
      float4 a1 = ef4[(size_t)e1 * 32 + l];
      a.x += a0.x + a1.x; a.y += a0.y + a1.y;
      a.z += a0.z + a1.z; a.w += a0.w + a1.w;
    }
    if (k < p1) {
      float4 a0 = ef4[(size_t)adj_n[k] * 32 + l];
      a.x += a0.x; a.y += a0.y; a.z += a0.z; a.w += a0.w;
    }
    float dinv = (p1 > p0) ? 1.0f / (float)(p1 - p0) : 0.0f;
    float4 v;
    v.x = fmaxf(fmaf(dinv, a.x, bc.x), 0.f);
    v.y = fmaxf(fmaf(dinv, a.y, bc.y), 0.f);
    v.z = fmaxf(fmaf(dinv, a.z, bc.z), 0.f);
    v.w = fmaxf(fmaf(dinv, a.w, bc.w), 0.f);
    ((float4*)z)[(size_t)i * 32 + l] = v;
    s1.x += v.x; s1.y += v.y; s1.z += v.z; s1.w += v.w;
    s2.x = fmaf(v.x, v.x, s2.x); s2.y = fmaf(v.y, v.y, s2.y);
    s2.z = fmaf(v.z, v.z, s2.z); s2.w = fmaf(v.w, v.w, s2.w);
  }
  int c0 = l * 4;
  atomicAdd(&lsum[c0 + 0], s1.x); atomicAdd(&lsum[c0 + 1], s1.y);
  atomicAdd(&lsum[c0 + 2], s1.z); atomicAdd(&lsum[c0 + 3], s1.w);
  atomicAdd(&lsumsq[c0 + 0], s2.x); atomicAdd(&lsumsq[c0 + 1], s2.y);
  atomicAdd(&lsumsq[c0 + 2], s2.z); atomicAdd(&lsumsq[c0 + 3], s2.w);
  __syncthreads();
  if (t < DIM) {
    atomicAdd(&sum[t], lsum[t]);
    atomicAdd(&sumsq[t], lsumsq[t]);
  }
}

// aff_a = g*rsqrt(var+eps); aff_d = beta - mu*aff_a
__global__ void finalize_bn_kernel(const float* __restrict__ sum,
                                   const float* __restrict__ sumsq,
                                   const float* __restrict__ g,
                                   const float* __restrict__ beta,
                                   float* __restrict__ aff_a, float* __restrict__ aff_d,
                                   int n) {
  int c = threadIdx.x;
  float inv_n = 1.0f / (float)n;
  float mu = sum[c] * inv_n;
  float var = fmaf(sumsq[c], inv_n, -mu * mu);
  float a = g[c] * rsqrtf(var + 1e-5f);
  aff_a[c] = a;
  aff_d[c] = fmaf(-mu, a, beta[c]);
}

// out = aff_a*z + aff_d (fp32, in-place safe: pure elementwise)
__global__ __launch_bounds__(256) void apply_affine_kernel(
    const float* __restrict__ zin, const float* __restrict__ aff_a,
    const float* __restrict__ aff_d, float* __restrict__ out, long total4) {
  long i = blockIdx.x * 256L + threadIdx.x;
  if (i >= total4) return;
  int c4 = (int)(i & 31);
  float4 a = ((const float4*)aff_a)[c4];
  float4 d = ((const float4*)aff_d)[c4];
  float4 v = ((const float4*)zin)[i];
  float4 o;
  o.x = fmaf(a.x, v.x, d.x);
  o.y = fmaf(a.y, v.y, d.y);
  o.z = fmaf(a.z, v.z, d.z);
  o.w = fmaf(a.w, v.w, d.w);
  ((float4*)out)[i] = o;
}

extern "C" void kernel_launch(void* const* d_in, const int* in_sizes, int n_in,
                              void* d_out, int out_size, void* d_ws, size_t ws_size,
                              hipStream_t stream) {
  const int NNZv = in_sizes[0] / 2;
  const int Nv   = in_sizes[1] / DIM;
  const int Ev   = in_sizes[2] / DIM;
  const int* eidx_raw = (const int*)d_in[0];
  const float* node_attr = (const float*)d_in[1];

  // ---- workspace layout (~21 MB total) ----
  float* bufE  = (float*)d_ws;                 // E*128 f32
  float* Wp    = bufE + (size_t)Ev * DIM;      // 128*128
  float* rvec  = Wp + DIM * DIM;               // 128
  float* sums  = rvec + 128;                   // 128
  float* sumsq = sums + 128;                   // 128
  float* aff_a = sumsq + 128;                  // 128
  float* aff_d = aff_a + 128;                  // 128
  int* src   = (int*)(aff_d + 128);            // NNZ
  int* edg   = src + NNZv;                     // NNZ
  int* P     = edg + NNZv;                     // E+N+1
  int* BS    = P + (Ev + Nv + 1);              // <=256 block sums
  int* cnt   = BS + 256;                       // E+N
  int* adj_e = cnt + (Ev + Nv);                // NNZ
  int* adj_n = adj_e + NNZv;                   // NNZ
  float* Ybuf = (float*)d_out;                 // Y and z time-share d_out

  const int M = Ev + Nv;
  const int nbA = cdiv(M, 1024);

  convert_idx_kernel<<<cdiv(2L * NNZv, 256), 256, 0, stream>>>(eidx_raw, src, 2L * NNZv);
  hipMemsetAsync(cnt, 0, (size_t)M * 4, stream);
  count_kernel<<<cdiv(NNZv, 256), 256, 0, stream>>>(src, edg, cnt, Ev, NNZv);
  scanA_kernel<<<nbA, 256, 0, stream>>>(cnt, P, BS, M);
  scanB_kernel<<<1, 64, 0, stream>>>(BS, P, nbA, M);
  scanC_kernel<<<cdiv(M, 256), 256, 0, stream>>>(P, BS, M);
  hipMemsetAsync(cnt, 0, (size_t)M * 4, stream);
  fill_adj_kernel<<<cdiv(NNZv, 256), 256, 0, stream>>>(src, edg, P, cnt, adj_e, adj_n, Ev, NNZv);

  const float* Xin = node_attr;
  for (int l = 0; l < 3; ++l) {
    const float* W    = (const float*)d_in[3 + l * 4];
    const float* b    = (const float*)d_in[4 + l * 4];
    const float* g    = (const float*)d_in[5 + l * 4];
    const float* beta = (const float*)d_in[6 + l * 4];

    prep_w_kernel<<<1, 128, 0, stream>>>(W, aff_a, aff_d, Wp, rvec, l > 0 ? 1 : 0);
    gemm128_kernel<<<cdiv(Nv, DIM), 256, 0, stream>>>(Xin, Wp, rvec, Ybuf, Nv);
    edge_gather_kernel<<<cdiv(Ev, 8), 256, 0, stream>>>(Ybuf, P, adj_e, bufE, Ev);
    hipMemsetAsync(sums, 0, 256 * 4, stream);
    node_gather_kernel<<<2048, 256, 0, stream>>>(bufE, P, adj_n, b, Ybuf, sums, sumsq,
                                                 Ev, Nv, NNZv);
    finalize_bn_kernel<<<1, 128, 0, stream>>>(sums, sumsq, g, beta, aff_a, aff_d, Nv);
    Xin = Ybuf;
  }
  apply_affine_kernel<<<cdiv((long)Nv * DIM / 4, 256), 256, 0, stream>>>(
      Ybuf, aff_a, aff_d, (float*)d_out, (long)Nv * DIM / 4);
}

// Round 5
// 912.811 us; speedup vs baseline: 1.3378x; 1.0875x over previous
//
#include <hip/hip_runtime.h>
#include <stdint.h>

#define DIM 128

static inline int cdiv(long a, long b) { return (int)((a + b - 1) / b); }

// ---- index conversion: handles both int32 and int64 edge_index layouts ----
__global__ __launch_bounds__(256) void convert_idx_kernel(
    const int* __restrict__ raw, int* __restrict__ out, long n_total) {
  bool is64;
  {
    int l = threadIdx.x & 63;
    int v = raw[2 * l + 1];               // high words if int64 (values < 2^31)
    unsigned long long m = __ballot(v == 0);
    is64 = (m == ~0ull);
  }
  long i = blockIdx.x * 256L + threadIdx.x;
  if (i < n_total) out[i] = is64 ? raw[2 * i] : raw[i];
}

// cnt[0..E) = hyperedge sizes, cnt[E..E+N) = node degrees
__global__ __launch_bounds__(256) void count_kernel(
    const int* __restrict__ src, const int* __restrict__ edg,
    int* __restrict__ cnt, int E, int nnz) {
  int g = blockIdx.x * 256 + threadIdx.x;
  if (g < nnz) {
    atomicAdd(&cnt[edg[g]], 1);
    atomicAdd(&cnt[E + src[g]], 1);
  }
}

// ---- 3-kernel exclusive scan of cnt[0..M) into P[0..M], P[M]=total ----
__global__ __launch_bounds__(256) void scanA_kernel(
    const int* __restrict__ cnt, int* __restrict__ P, int* __restrict__ BS, int M) {
  __shared__ int lds[256];
  int t = threadIdx.x;
  long base = blockIdx.x * 1024L;
  int v[4], ts = 0;
#pragma unroll
  for (int j = 0; j < 4; ++j) {
    long i = base + t * 4 + j;
    v[j] = (i < M) ? cnt[i] : 0;
    ts += v[j];
  }
  lds[t] = ts;
  __syncthreads();
  for (int off = 1; off < 256; off <<= 1) {
    int x = (t >= off) ? lds[t - off] : 0;
    __syncthreads();
    lds[t] += x;
    __syncthreads();
  }
  int run = lds[t] - ts;  // exclusive base for this thread
#pragma unroll
  for (int j = 0; j < 4; ++j) {
    long i = base + t * 4 + j;
    if (i < M) P[i] = run;
    run += v[j];
  }
  if (t == 255) BS[blockIdx.x] = lds[255];
}

__global__ void scanB_kernel(int* __restrict__ BS, int* __restrict__ P,
                             int nblocks, int M) {
  if (threadIdx.x == 0) {
    int run = 0;
    for (int i = 0; i < nblocks; ++i) { int x = BS[i]; BS[i] = run; run += x; }
    P[M] = run;
  }
}

__global__ __launch_bounds__(256) void scanC_kernel(
    int* __restrict__ P, const int* __restrict__ BS, int M) {
  long i = blockIdx.x * 256L + threadIdx.x;
  if (i < M) P[i] += BS[i >> 10];
}

// adj_e[P[e]..] = member nodes of edge e ; adj_n[P[E+i]-nnz..] = edges of node i
__global__ __launch_bounds__(256) void fill_adj_kernel(
    const int* __restrict__ src, const int* __restrict__ edg,
    const int* __restrict__ P, int* __restrict__ cnt,
    int* __restrict__ adj_e, int* __restrict__ adj_n, int E, int nnz) {
  int g = blockIdx.x * 256 + threadIdx.x;
  if (g < nnz) {
    int e = edg[g], s = src[g];
    int pe = P[e] + atomicAdd(&cnt[e], 1);
    adj_e[pe] = s;
    int pn = P[E + s] - nnz + atomicAdd(&cnt[E + s], 1);
    adj_n[pn] = e;
  }
}

// Wp = diag(a) @ W ; rvec = d @ W   (folds previous layer's BN affine into GEMM)
__global__ void prep_w_kernel(const float* __restrict__ W,
                              const float* __restrict__ aff_a,
                              const float* __restrict__ aff_d,
                              float* __restrict__ Wp, float* __restrict__ rvec,
                              int has_aff) {
  int j = threadIdx.x;  // 0..127
  float racc = 0.0f;
  for (int c = 0; c < DIM; ++c) {
    float w = W[c * DIM + j];
    float a = has_aff ? aff_a[c] : 1.0f;
    float d = has_aff ? aff_d[c] : 0.0f;
    Wp[c * DIM + j] = a * w;
    racc = fmaf(d, w, racc);
  }
  rvec[j] = racc;
}

// ag[e][c] = Binv_e * sum_{i in e} X[i][c]   (pure sum of z / node_attr rows)
// 32 lanes/edge (float4), 8 edge-slots per 256-thread block, 4x unroll.
__global__ __launch_bounds__(256) void edge_gather_kernel(
    const float* __restrict__ X, const int* __restrict__ P,
    const int* __restrict__ adj_e, float* __restrict__ ag, int E) {
  int slot = threadIdx.x >> 5;
  int l = threadIdx.x & 31;
  int e = blockIdx.x * 8 + slot;
  if (e >= E) return;
  int p0 = P[e], p1 = P[e + 1];
  const float4* X4 = (const float4*)X;
  float4 acc = {0.f, 0.f, 0.f, 0.f};
  int k = p0;
  for (; k + 3 < p1; k += 4) {
    int n0 = adj_e[k], n1 = adj_e[k + 1], n2 = adj_e[k + 2], n3 = adj_e[k + 3];
    float4 a0 = X4[(size_t)n0 * 32 + l];
    float4 a1 = X4[(size_t)n1 * 32 + l];
    float4 a2 = X4[(size_t)n2 * 32 + l];
    float4 a3 = X4[(size_t)n3 * 32 + l];
    acc.x += (a0.x + a1.x) + (a2.x + a3.x);
    acc.y += (a0.y + a1.y) + (a2.y + a3.y);
    acc.z += (a0.z + a1.z) + (a2.z + a3.z);
    acc.w += (a0.w + a1.w) + (a2.w + a3.w);
  }
  for (; k < p1; ++k) {
    float4 a0 = X4[(size_t)adj_e[k] * 32 + l];
    acc.x += a0.x; acc.y += a0.y; acc.z += a0.z; acc.w += a0.w;
  }
  float binv = (p1 > p0) ? 1.0f / (float)(p1 - p0) : 0.0f;
  acc.x *= binv; acc.y *= binv; acc.z *= binv; acc.w *= binv;
  ((float4*)ag)[(size_t)e * 32 + l] = acc;
}

// ef[E x 128] = ag @ Wp + rvec (all fp32), zeroed for empty edges (deg==0).
// In-place safe (ag == ef): each block reads only its own 128 rows, and all
// its global reads complete before any of its stores.
__global__ __launch_bounds__(256) void gemm128_kernel(
    const float* __restrict__ X, const float* __restrict__ Wp,
    const float* __restrict__ rvec, const int* __restrict__ Pdeg,
    float* __restrict__ Y, int nrows) {
  __shared__ float sW[32 * DIM];   // sW[kk*128 + j]
  __shared__ float sX[DIM * 36];   // sX[rr*36 + kk], 36 keeps 16B align + pad
  const int t = threadIdx.x;
  const int row0 = blockIdx.x * DIM;
  const int tx = t & 15, ty = t >> 4;
  const int col0 = tx * 8, lr0 = ty * 8;
  float acc[8][8];
#pragma unroll
  for (int i = 0; i < 8; ++i)
#pragma unroll
    for (int j = 0; j < 8; ++j) acc[i][j] = 0.0f;

  for (int kc = 0; kc < 4; ++kc) {
    __syncthreads();
    {
      const float4* W4 = (const float4*)(Wp + kc * 32 * DIM);
      float4* sW4 = (float4*)sW;
#pragma unroll
      for (int i = 0; i < 4; ++i) sW4[t + i * 256] = W4[t + i * 256];
    }
#pragma unroll
    for (int i = 0; i < 4; ++i) {
      int q = t + i * 256;            // 0..1023 float4 slots
      int rr = q >> 3, kq = q & 7;
      int gr = row0 + rr; if (gr >= nrows) gr = nrows - 1;  // stores are guarded
      float4 v = *(const float4*)&X[(size_t)gr * DIM + kc * 32 + kq * 4];
      *(float4*)&sX[rr * 36 + kq * 4] = v;
    }
    __syncthreads();
    for (int kk = 0; kk < 32; ++kk) {
      float4 w0 = *(const float4*)&sW[kk * DIM + col0];
      float4 w1 = *(const float4*)&sW[kk * DIM + col0 + 4];
      float wv[8] = {w0.x, w0.y, w0.z, w0.w, w1.x, w1.y, w1.z, w1.w};
      float xv[8];
#pragma unroll
      for (int i = 0; i < 8; ++i) xv[i] = sX[(lr0 + i) * 36 + kk];
#pragma unroll
      for (int i = 0; i < 8; ++i)
#pragma unroll
        for (int j = 0; j < 8; ++j) acc[i][j] = fmaf(xv[i], wv[j], acc[i][j]);
    }
  }
  float4 r0 = *(const float4*)&rvec[col0];
  float4 r1 = *(const float4*)&rvec[col0 + 4];
#pragma unroll
  for (int i = 0; i < 8; ++i) {
    int gr = row0 + lr0 + i;
    if (gr < nrows) {
      // empty segment must produce 0 (reference: Binv=0 ⇒ e_feat=0),
      // not rvec — guard with the degree.
      float nz = (Pdeg[gr + 1] > Pdeg[gr]) ? 1.0f : 0.0f;
      float4 o0, o1;
      o0.x = (acc[i][0] + r0.x) * nz; o0.y = (acc[i][1] + r0.y) * nz;
      o0.z = (acc[i][2] + r0.z) * nz; o0.w = (acc[i][3] + r0.w) * nz;
      o1.x = (acc[i][4] + r1.x) * nz; o1.y = (acc[i][5] + r1.y) * nz;
      o1.z = (acc[i][6] + r1.z) * nz; o1.w = (acc[i][7] + r1.w) * nz;
      *(float4*)&Y[(size_t)gr * DIM + col0]     = o0;
      *(float4*)&Y[(size_t)gr * DIM + col0 + 4] = o1;
    }
  }
}

// z[i][c] = relu(Dinv_i * sum_{e ni i} ef[e][c] + b_c), fused BN stats.
// 32 lanes/node (float4), 8 node-slots per block, grid-stride, 4x unroll.
__global__ __launch_bounds__(256) void node_gather_kernel(
    const float* __restrict__ ef, const int* __restrict__ P,
    const int* __restrict__ adj_n, const float* __restrict__ b,
    float* __restrict__ z, float* __restrict__ sum,
    float* __restrict__ sumsq, int E, int N, int nnz) {
  __shared__ float lsum[DIM], lsumsq[DIM];
  int t = threadIdx.x;
  if (t < DIM) { lsum[t] = 0.f; lsumsq[t] = 0.f; }
  __syncthreads();
  int slot = t >> 5;
  int l = t & 31;
  const float4* ef4 = (const float4*)ef;
  float4 bc = ((const float4*)b)[l];
  float4 s1 = {0.f, 0.f, 0.f, 0.f}, s2 = {0.f, 0.f, 0.f, 0.f};
  for (int i = blockIdx.x * 8 + slot; i < N; i += gridDim.x * 8) {
    int p0 = P[E + i] - nnz, p1 = P[E + i + 1] - nnz;
    float4 a = {0.f, 0.f, 0.f, 0.f};
    int k = p0;
    for (; k + 3 < p1; k += 4) {
      int e0 = adj_n[k], e1 = adj_n[k + 1], e2 = adj_n[k + 2], e3 = adj_n[k + 3];
      float4 a0 = ef4[(size_t)e0 * 32 + l];
      float4 a1 = ef4[(size_t)e1 * 32 + l];
      float4 a2 = ef4[(size_t)e2 * 32 + l];
      float4 a3 = ef4[(size_t)e3 * 32 + l];
      a.x += (a0.x + a1.x) + (a2.x + a3.x);
      a.y += (a0.y + a1.y) + (a2.y + a3.y);
      a.z += (a0.z + a1.z) + (a2.z + a3.z);
      a.w += (a0.w + a1.w) + (a2.w + a3.w);
    }
    for (; k < p1; ++k) {
      float4 a0 = ef4[(size_t)adj_n[k] * 32 + l];
      a.x += a0.x; a.y += a0.y; a.z += a0.z; a.w += a0.w;
    }
    float dinv = (p1 > p0) ? 1.0f / (float)(p1 - p0) : 0.0f;
    float4 v;
    v.x = fmaxf(fmaf(dinv, a.x, bc.x), 0.f);
    v.y = fmaxf(fmaf(dinv, a.y, bc.y), 0.f);
    v.z = fmaxf(fmaf(dinv, a.z, bc.z), 0.f);
    v.w = fmaxf(fmaf(dinv, a.w, bc.w), 0.f);
    ((float4*)z)[(size_t)i * 32 + l] = v;
    s1.x += v.x; s1.y += v.y; s1.z += v.z; s1.w += v.w;
    s2.x = fmaf(v.x, v.x, s2.x); s2.y = fmaf(v.y, v.y, s2.y);
    s2.z = fmaf(v.z, v.z, s2.z); s2.w = fmaf(v.w, v.w, s2.w);
  }
  int c0 = l * 4;
  atomicAdd(&lsum[c0 + 0], s1.x); atomicAdd(&lsum[c0 + 1], s1.y);
  atomicAdd(&lsum[c0 + 2], s1.z); atomicAdd(&lsum[c0 + 3], s1.w);
  atomicAdd(&lsumsq[c0 + 0], s2.x); atomicAdd(&lsumsq[c0 + 1], s2.y);
  atomicAdd(&lsumsq[c0 + 2], s2.z); atomicAdd(&lsumsq[c0 + 3], s2.w);
  __syncthreads();
  if (t < DIM) {
    atomicAdd(&sum[t], lsum[t]);
    atomicAdd(&sumsq[t], lsumsq[t]);
  }
}

// aff_a = g*rsqrt(var+eps); aff_d = beta - mu*aff_a
__global__ void finalize_bn_kernel(const float* __restrict__ sum,
                                   const float* __restrict__ sumsq,
                                   const float* __restrict__ g,
                                   const float* __restrict__ beta,
                                   float* __restrict__ aff_a, float* __restrict__ aff_d,
                                   int n) {
  int c = threadIdx.x;
  float inv_n = 1.0f / (float)n;
  float mu = sum[c] * inv_n;
  float var = fmaf(sumsq[c], inv_n, -mu * mu);
  float a = g[c] * rsqrtf(var + 1e-5f);
  aff_a[c] = a;
  aff_d[c] = fmaf(-mu, a, beta[c]);
}

// out = aff_a*z + aff_d (fp32, in-place safe: pure elementwise)
__global__ __launch_bounds__(256) void apply_affine_kernel(
    const float* __restrict__ zin, const float* __restrict__ aff_a,
    const float* __restrict__ aff_d, float* __restrict__ out, long total4) {
  long i = blockIdx.x * 256L + threadIdx.x;
  if (i >= total4) return;
  int c4 = (int)(i & 31);
  float4 a = ((const float4*)aff_a)[c4];
  float4 d = ((const float4*)aff_d)[c4];
  float4 v = ((const float4*)zin)[i];
  float4 o;
  o.x = fmaf(a.x, v.x, d.x);
  o.y = fmaf(a.y, v.y, d.y);
  o.z = fmaf(a.z, v.z, d.z);
  o.w = fmaf(a.w, v.w, d.w);
  ((float4*)out)[i] = o;
}

extern "C" void kernel_launch(void* const* d_in, const int* in_sizes, int n_in,
                              void* d_out, int out_size, void* d_ws, size_t ws_size,
                              hipStream_t stream) {
  const int NNZv = in_sizes[0] / 2;
  const int Nv   = in_sizes[1] / DIM;
  const int Ev   = in_sizes[2] / DIM;
  const int* eidx_raw = (const int*)d_in[0];
  const float* node_attr = (const float*)d_in[1];

  // ---- workspace layout (~21 MB total) ----
  float* bufE  = (float*)d_ws;                 // E*128 f32 (ag, then ef in-place)
  float* Wp    = bufE + (size_t)Ev * DIM;      // 128*128
  float* rvec  = Wp + DIM * DIM;               // 128
  float* sums  = rvec + 128;                   // 128
  float* sumsq = sums + 128;                   // 128
  float* aff_a = sumsq + 128;                  // 128
  float* aff_d = aff_a + 128;                  // 128
  int* src   = (int*)(aff_d + 128);            // NNZ
  int* edg   = src + NNZv;                     // NNZ
  int* P     = edg + NNZv;                     // E+N+1
  int* BS    = P + (Ev + Nv + 1);              // <=256 block sums
  int* cnt   = BS + 256;                       // E+N
  int* adj_e = cnt + (Ev + Nv);                // NNZ
  int* adj_n = adj_e + NNZv;                   // NNZ
  float* Ybuf = (float*)d_out;                 // z time-shares d_out

  const int M = Ev + Nv;
  const int nbA = cdiv(M, 1024);

  convert_idx_kernel<<<cdiv(2L * NNZv, 256), 256, 0, stream>>>(eidx_raw, src, 2L * NNZv);
  hipMemsetAsync(cnt, 0, (size_t)M * 4, stream);
  count_kernel<<<cdiv(NNZv, 256), 256, 0, stream>>>(src, edg, cnt, Ev, NNZv);
  scanA_kernel<<<nbA, 256, 0, stream>>>(cnt, P, BS, M);
  scanB_kernel<<<1, 64, 0, stream>>>(BS, P, nbA, M);
  scanC_kernel<<<cdiv(M, 256), 256, 0, stream>>>(P, BS, M);
  hipMemsetAsync(cnt, 0, (size_t)M * 4, stream);
  fill_adj_kernel<<<cdiv(NNZv, 256), 256, 0, stream>>>(src, edg, P, cnt, adj_e, adj_n, Ev, NNZv);

  const float* Xin = node_attr;
  for (int l = 0; l < 3; ++l) {
    const float* W    = (const float*)d_in[3 + l * 4];
    const float* b    = (const float*)d_in[4 + l * 4];
    const float* g    = (const float*)d_in[5 + l * 4];
    const float* beta = (const float*)d_in[6 + l * 4];

    prep_w_kernel<<<1, 128, 0, stream>>>(W, aff_a, aff_d, Wp, rvec, l > 0 ? 1 : 0);
    // ag[e] = Binv * sum of x rows  (GEMM moved to edge level: 5x fewer FLOPs)
    edge_gather_kernel<<<cdiv(Ev, 8), 256, 0, stream>>>(Xin, P, adj_e, bufE, Ev);
    gemm128_kernel<<<cdiv(Ev, DIM), 256, 0, stream>>>(bufE, Wp, rvec, P, bufE, Ev);
    hipMemsetAsync(sums, 0, 256 * 4, stream);
    node_gather_kernel<<<2048, 256, 0, stream>>>(bufE, P, adj_n, b, Ybuf, sums, sumsq,
                                                 Ev, Nv, NNZv);
    finalize_bn_kernel<<<1, 128, 0, stream>>>(sums, sumsq, g, beta, aff_a, aff_d, Nv);
    Xin = Ybuf;
  }
  apply_affine_kernel<<<cdiv((long)Nv * DIM / 4, 256), 256, 0, stream>>>(
      Ybuf, aff_a, aff_d, (float*)d_out, (long)Nv * DIM / 4);
}